// Round 11
// baseline (551.770 us; speedup 1.0000x reference)
//
#include <hip/hip_runtime.h>
#include <hip/hip_bf16.h>

#define D 128
#define SLOTS 64
#define CSTR 72     // colidx row stride; slots [deg,CSTR) hold dummy index N
#define BCAP 9216   // bucket capacity: mean 8192, +11 sigma

typedef short short8 __attribute__((ext_vector_type(8)));
typedef float f32x4 __attribute__((ext_vector_type(4)));
typedef unsigned short u16;
typedef unsigned int u32;

#define AS1 __attribute__((address_space(1)))
#define AS3 __attribute__((address_space(3)))

static __device__ __forceinline__ u16 f2bf(float f) {
  union { float f; unsigned u; } v; v.f = f;
  unsigned r = v.u + 0x7FFF + ((v.u >> 16) & 1);  // round-to-nearest-even
  return (u16)(r >> 16);
}
static __device__ __forceinline__ float bf2f(u16 h) {
  union { unsigned u; float f; } v; v.u = ((unsigned)h) << 16;
  return v.f;
}

// ---------- merged prep: binA | convertW | convertX(panel) | zero-rows ----------
__global__ __launch_bounds__(1024) void prep_kernel(
    const int* __restrict__ src, const int* __restrict__ dst,
    const float* __restrict__ x, const float* __restrict__ W1,
    const float* __restrict__ W2, int* __restrict__ gcount,
    u32* __restrict__ bedge, u16* __restrict__ W1th, u16* __restrict__ W1tl,
    u16* __restrict__ W2th, u16* __restrict__ W2tl, u32* __restrict__ xp,
    u32* __restrict__ hp, int E, int nbk, int wtotal, int nPairs,
    int nA, int nB, int nC, int N, int rowsP) {
  __shared__ int cnt[128];
  __shared__ int base[128];
  int b = blockIdx.x, t = threadIdx.x;
  if (b < nA) {
    // binA: LDS-binned edge scatter into 512-node dst-buckets
    if (t < nbk) cnt[t] = 0;
    __syncthreads();
    int e = b * 1024 + t;
    int bk = 0, p = 0;
    u32 payload = 0;
    bool valid = e < E;
    if (valid) {
      int d = dst[e];
      bk = d >> 9;
      payload = ((u32)src[e] << 9) | (u32)(d & 511);
      p = atomicAdd(&cnt[bk], 1);      // LDS atomic
    }
    __syncthreads();
    if (t < nbk) base[t] = cnt[t] ? atomicAdd(&gcount[t], cnt[t]) : 0;
    __syncthreads();
    if (valid) {
      int pos = base[bk] + p;
      if (pos < BCAP) bedge[(size_t)bk * BCAP + pos] = payload;
    }
  } else if (b < nA + nB) {
    // convert weights: hi/lo split bf16 in MFMA-fragment-tiled order
    int idx = (b - nA) * 1024 + t;
    if (idx < wtotal) {
      int l = idx >> 14;
      int r = idx & 16383;
      int j = r & 7;
      int lane = (r >> 3) & 63;
      int tt = r >> 9;
      int kt = tt >> 3, nt = tt & 7;
      int k = kt * 32 + (lane >> 4) * 8 + j;
      int n = nt * 16 + (lane & 15);
      size_t s = (size_t)l * D * D + (size_t)k * D + n;
      float w1 = W1[s], w2 = W2[s];
      u16 h1 = f2bf(w1), h2 = f2bf(w2);
      W1th[idx] = h1; W1tl[idx] = f2bf(w1 - bf2f(h1));
      W2th[idx] = h2; W2tl[idx] = f2bf(w2 - bf2f(h2));
    }
  } else if (b < nA + nB + nC) {
    // convert x -> bf16 packed pairs, panel-major xp[p][node][8 u32]
    int i = (b - nA - nB) * 1024 + t;
    if (i < nPairs) {
      int node = i >> 6, pr = i & 63;
      float2 v = ((const float2*)x)[i];
      u32 pk = ((u32)f2bf(v.y) << 16) | f2bf(v.x);
      xp[((size_t)(pr >> 3) * rowsP + node) * 8 + (pr & 7)] = pk;
    }
  } else {
    // zero dummy row N of all panels of xp and hp
    if (t < 64) {
      xp[((size_t)(t >> 3) * rowsP + N) * 8 + (t & 7)] = 0;
      hp[((size_t)(t >> 3) * rowsP + N) * 8 + (t & 7)] = 0;
    }
  }
}

// ---------- binB: per-bucket slot assignment (LDS counters) + slot padding ----------
__global__ __launch_bounds__(1024) void binB_kernel(
    const int* __restrict__ gcount, const u32* __restrict__ bedge,
    int* __restrict__ deg, int* __restrict__ colidx, int N) {
  __shared__ int cnt2[512];
  int b = blockIdx.x;
  int t = threadIdx.x;
  if (t < 512) cnt2[t] = 0;
  __syncthreads();
  int count = min(gcount[b], BCAP);
  const u32* lst = bedge + (size_t)b * BCAP;
  for (int i = t; i < count; i += 1024) {
    u32 v = lst[i];
    int local = v & 511;
    int slot = atomicAdd(&cnt2[local], 1);   // LDS atomic
    if (slot < SLOTS)
      colidx[((size_t)(b << 9) + local) * CSTR + slot] = (int)(v >> 9);
  }
  __syncthreads();
  if (t < 512) {
    int node = (b << 9) + t;
    if (node < N) deg[node] = min(cnt2[t], SLOTS);
  }
  // pad slots [deg, CSTR) with dummy index N (zero row)
  for (int i = t; i < 512 * CSTR; i += 1024) {
    int local = i / CSTR;
    int slot = i - local * CSTR;
    int node = (b << 9) + local;
    if (node < N && slot >= min(cnt2[local], SLOTS))
      colidx[((size_t)(b << 9) + local) * CSTR + slot] = N;
  }
}

// ---------- panel aggregation: z = h + sum_{j->i} h[j], per 16-col panel ----------
// blockIdx&7 = panel; same panel lands on same XCD under round-robin dispatch, so
// the 1.6 MB panel stays L2-resident (kills the 8x h broadcast seen via FETCH_SIZE).
// Wave: 8 lanes/node (lane j = cols 2j,2j+1), 8 nodes/wave, 8-deep gather unroll.
__global__ __launch_bounds__(256) void aggregate_kernel(
    const u32* __restrict__ hp, const int* __restrict__ deg,
    const int* __restrict__ colidx, u32* __restrict__ zp, int N, int rowsP) {
  int p = blockIdx.x & 7;
  int chunk = blockIdx.x >> 3;
  int lane = threadIdx.x & 63;
  int wave = threadIdx.x >> 6;
  int g = lane >> 3, j = lane & 7;
  const u32* hpp = hp + (size_t)p * rowsP * 8;
  u32* zpp = zp + (size_t)p * rowsP * 8;
#pragma unroll 1
  for (int it = 0; it < 8; ++it) {
    int node = chunk * 256 + wave * 64 + it * 8 + g;
    bool live = node < N;
    int e = live ? deg[node] : 0;
    int e8 = (e + 7) & ~7;
    const int* nbr = colidx + (size_t)(live ? node : 0) * CSTR;
    u32 self = hpp[(size_t)(live ? node : N) * 8 + j];
    float a0 = bf2f((u16)(self & 0xffff));
    float a1 = bf2f((u16)(self >> 16));
    for (int k = 0; k < e8; k += 8) {
      int idx[8];
      u32 v[8];
#pragma unroll
      for (int i = 0; i < 8; ++i) idx[i] = nbr[k + i];   // 8-lane broadcast each
#pragma unroll
      for (int i = 0; i < 8; ++i) v[i] = hpp[(size_t)idx[i] * 8 + j];
#pragma unroll
      for (int i = 0; i < 8; ++i) {
        a0 += bf2f((u16)(v[i] & 0xffff));
        a1 += bf2f((u16)(v[i] >> 16));
      }
    }
    if (live) zpp[(size_t)node * 8 + j] = ((u32)f2bf(a1) << 16) | f2bf(a0);
  }
}

// ---------- GEMM: out = relu(A @ W + b) ----------
// W staged to LDS (64KB hi/lo, fragment-tiled, conflict-free), staggered DMA,
// 256 rows/block x 512 thr, A-frags hoisted above the barrier (r9-proven).
// STAGE 0: A panel-major (zp) -> y row-major.
// STAGE 1: A row-major (y)    -> h panel-major.
// STAGE 2: A row-major (y)    -> fused relu(.)·Wh dot -> atomic gsum[batch[row]].
template <int STAGE>
__global__ __launch_bounds__(512) void gemm_kernel(
    const u16* __restrict__ A, const u16* __restrict__ Wth, const u16* __restrict__ Wtl,
    const float* __restrict__ bias, u16* __restrict__ outp,
    const float* __restrict__ Wh, const int* __restrict__ batch, float* __restrict__ gsum,
    int nrows, int rowsP) {
  __shared__ __attribute__((aligned(16))) u16 ldsWh[16384];
  __shared__ __attribute__((aligned(16))) u16 ldsWl[16384];
  {
    int it0 = blockIdx.x & 3;
    int off = threadIdx.x * 16;
#pragma unroll
    for (int it = 0; it < 4; ++it) {
      int o = ((it + it0) & 3) * 8192 + off;
      __builtin_amdgcn_global_load_lds((const AS1 unsigned*)((const char*)Wth + o),
                                       (AS3 unsigned*)((char*)ldsWh + o), 16, 0, 0);
      __builtin_amdgcn_global_load_lds((const AS1 unsigned*)((const char*)Wtl + o),
                                       (AS3 unsigned*)((char*)ldsWl + o), 16, 0, 0);
    }
  }
  int wave = threadIdx.x >> 6, lane = threadIdx.x & 63;
  int quad = lane >> 4, l16 = lane & 15;
  int rowbase = blockIdx.x * 256 + wave * 32;
  int mc0 = min(rowbase + l16, nrows - 1);
  int mc1 = min(rowbase + 16 + l16, nrows - 1);

  // preload all A-fragments; latency rides the W DMA drain at the barrier
  short8 a0[4], a1[4];
#pragma unroll
  for (int kt = 0; kt < 4; ++kt) {
    if (STAGE == 0) {
      const u16* base = A + ((size_t)(2 * kt + (quad >> 1)) * rowsP) * 16 + (quad & 1) * 8;
      a0[kt] = *(const short8*)(base + (size_t)mc0 * 16);
      a1[kt] = *(const short8*)(base + (size_t)mc1 * 16);
    } else {
      a0[kt] = *(const short8*)(A + (size_t)mc0 * D + kt * 32 + quad * 8);
      a1[kt] = *(const short8*)(A + (size_t)mc1 * D + kt * 32 + quad * 8);
    }
  }

  __syncthreads();

  f32x4 acc[2][8];
  f32x4 zero = {0.f, 0.f, 0.f, 0.f};
#pragma unroll
  for (int mt = 0; mt < 2; ++mt)
#pragma unroll
    for (int nt = 0; nt < 8; ++nt) acc[mt][nt] = zero;

#pragma unroll
  for (int kt = 0; kt < 4; ++kt) {
#pragma unroll
    for (int nt = 0; nt < 8; ++nt) {
      int fo = ((kt * 8 + nt) * 64 + lane) * 8;
      short8 bh = *(const short8*)(ldsWh + fo);
      short8 bl = *(const short8*)(ldsWl + fo);
      acc[0][nt] = __builtin_amdgcn_mfma_f32_16x16x32_bf16(a0[kt], bh, acc[0][nt], 0, 0, 0);
      acc[0][nt] = __builtin_amdgcn_mfma_f32_16x16x32_bf16(a0[kt], bl, acc[0][nt], 0, 0, 0);
      acc[1][nt] = __builtin_amdgcn_mfma_f32_16x16x32_bf16(a1[kt], bh, acc[1][nt], 0, 0, 0);
      acc[1][nt] = __builtin_amdgcn_mfma_f32_16x16x32_bf16(a1[kt], bl, acc[1][nt], 0, 0, 0);
    }
  }

  if (STAGE == 2) {
    float dotr[2][4] = {{0.f, 0.f, 0.f, 0.f}, {0.f, 0.f, 0.f, 0.f}};
#pragma unroll
    for (int nt = 0; nt < 8; ++nt) {
      int col = nt * 16 + l16;
      float bv = bias[col];
      float wv = Wh[col];
#pragma unroll
      for (int mt = 0; mt < 2; ++mt)
#pragma unroll
        for (int r = 0; r < 4; ++r)
          dotr[mt][r] += fmaxf(acc[mt][nt][r] + bv, 0.f) * wv;
    }
#pragma unroll
    for (int m = 1; m < 16; m <<= 1) {
#pragma unroll
      for (int mt = 0; mt < 2; ++mt)
#pragma unroll
        for (int r = 0; r < 4; ++r) dotr[mt][r] += __shfl_xor(dotr[mt][r], m, 64);
    }
    if (l16 == 0) {
#pragma unroll
      for (int mt = 0; mt < 2; ++mt)
#pragma unroll
        for (int r = 0; r < 4; ++r) {
          int row = rowbase + mt * 16 + quad * 4 + r;
          if (row < nrows) atomicAdd(&gsum[batch[row]], dotr[mt][r]);
        }
    }
  } else {
#pragma unroll
    for (int nt = 0; nt < 8; ++nt) {
      int col = nt * 16 + l16;
      float bv = bias[col];
#pragma unroll
      for (int mt = 0; mt < 2; ++mt)
#pragma unroll
        for (int r = 0; r < 4; ++r) {
          int row = rowbase + mt * 16 + quad * 4 + r;
          if (row < nrows) {
            float v = fmaxf(acc[mt][nt][r] + bv, 0.f);
            if (STAGE == 0) outp[(size_t)row * D + col] = f2bf(v);
            else outp[((size_t)nt * rowsP + row) * 16 + l16] = f2bf(v);
          }
        }
    }
  }
}

// ---------- finalize: per-graph mean via binary search on sorted batch ----------
__global__ void pool_final_kernel(const float* __restrict__ gsum, const int* __restrict__ batch,
                                  const float* __restrict__ bh, float* __restrict__ out,
                                  int G, int N) {
  int g = blockIdx.x * 256 + threadIdx.x;
  if (g >= G) return;
  int lo = 0, hi = N;
  while (lo < hi) { int mid = (lo + hi) >> 1; if (batch[mid] < g) lo = mid + 1; else hi = mid; }
  int lo2 = lo, hi2 = N;
  while (lo2 < hi2) { int mid = (lo2 + hi2) >> 1; if (batch[mid] < g + 1) lo2 = mid + 1; else hi2 = mid; }
  int c = lo2 - lo;
  out[g] = gsum[g] / fmaxf((float)c, 1.f) + bh[0];
}

extern "C" void kernel_launch(void* const* d_in, const int* in_sizes, int n_in,
                              void* d_out, int out_size, void* d_ws, size_t ws_size,
                              hipStream_t stream) {
  const float* x   = (const float*)d_in[0];
  const int* eidx  = (const int*)d_in[1];
  const int* batch = (const int*)d_in[2];
  const float* W1s = (const float*)d_in[3];
  const float* b1s = (const float*)d_in[4];
  const float* W2s = (const float*)d_in[5];
  const float* b2s = (const float*)d_in[6];
  const float* Wh  = (const float*)d_in[7];
  const float* bh  = (const float*)d_in[8];
  float* out = (float*)d_out;

  int N = in_sizes[0] / D;
  int E = in_sizes[1] / 2;
  int G = out_size;
  int L = in_sizes[3] / (D * D);
  int nbk = (N + 511) >> 9;           // 512-node dst-buckets (<=128)
  int wtotal = L * D * D;
  int nPairs = N * D / 2;
  int rowsP = N + 1;                  // panel rows incl. zero dummy row

  const int* src = eidx;
  const int* dst = eidx + E;

  char* p = (char*)d_ws;
  auto alloc = [&](size_t b) { char* r = p; p += (b + 255) & ~(size_t)255; return r; };
  u16*   hpnl   = (u16*)  alloc((size_t)8 * rowsP * 16 * 2);  // panel-major h
  u16*   xpnl   = (u16*)  alloc((size_t)8 * rowsP * 16 * 2);  // panel-major x(bf16)
  u16*   zpnl   = (u16*)  alloc((size_t)8 * rowsP * 16 * 2);  // panel-major z
  u16*   yb     = (u16*)  alloc((size_t)N * D * 2);           // row-major y
  size_t zbytes = (size_t)G * 4 + 512;                        // gsum + gcount
  char*  zblk   =         alloc(zbytes);
  float* gsum   = (float*)zblk;
  int*   gcount = (int*)(zblk + (size_t)G * 4);
  int*   deg    = (int*)  alloc((size_t)N * 4);
  int*   colidx = (int*)  alloc((size_t)N * CSTR * 4);
  u32*   bedge  = (u32*)  alloc((size_t)128 * BCAP * 4);
  u16*   W1th   = (u16*)  alloc((size_t)L * D * D * 2);
  u16*   W1tl   = (u16*)  alloc((size_t)L * D * D * 2);
  u16*   W2th   = (u16*)  alloc((size_t)L * D * D * 2);
  u16*   W2tl   = (u16*)  alloc((size_t)L * D * D * 2);

  hipMemsetAsync(zblk, 0, zbytes, stream);

  int nA = (E + 1023) / 1024;
  int nB = (wtotal + 1023) / 1024;
  int nC = (nPairs + 1023) / 1024;
  prep_kernel<<<nA + nB + nC + 1, 1024, 0, stream>>>(
      src, dst, x, W1s, W2s, gcount, bedge, W1th, W1tl, W2th, W2tl,
      (u32*)xpnl, (u32*)hpnl, E, nbk, wtotal, nPairs, nA, nB, nC, N, rowsP);
  binB_kernel<<<nbk, 1024, 0, stream>>>(gcount, bedge, deg, colidx, N);

  int agg_blocks = 8 * ((N + 255) / 256);
  int gemm_blocks = (N + 255) / 256;
  for (int l = 0; l < L; ++l) {
    const u16* hin = (l == 0) ? xpnl : hpnl;
    size_t wo = (size_t)l * D * D;
    aggregate_kernel<<<agg_blocks, 256, 0, stream>>>(
        (const u32*)hin, deg, colidx, (u32*)zpnl, N, rowsP);
    gemm_kernel<0><<<gemm_blocks, 512, 0, stream>>>(
        zpnl, W1th + wo, W1tl + wo, b1s + (size_t)l * D, yb,
        nullptr, nullptr, nullptr, N, rowsP);
    if (l < L - 1) {
      gemm_kernel<1><<<gemm_blocks, 512, 0, stream>>>(
          yb, W2th + wo, W2tl + wo, b2s + (size_t)l * D, hpnl,
          nullptr, nullptr, nullptr, N, rowsP);
    } else {
      gemm_kernel<2><<<gemm_blocks, 512, 0, stream>>>(
          yb, W2th + wo, W2tl + wo, b2s + (size_t)l * D, nullptr,
          Wh, batch, gsum, N, rowsP);
    }
  }
  pool_final_kernel<<<(G + 255) / 256, 256, 0, stream>>>(gsum, batch, bh, out, G, N);
}

// Round 12
// 438.913 us; speedup vs baseline: 1.2571x; 1.2571x over previous
//
#include <hip/hip_runtime.h>
#include <hip/hip_bf16.h>

#define D 128
#define SLOTS 64
#define CSTR 72     // colidx row stride; slots [deg,CSTR) hold dummy index N
#define BCAP 9216   // bucket capacity: mean 8192, +11 sigma

typedef short short8 __attribute__((ext_vector_type(8)));
typedef float f32x4 __attribute__((ext_vector_type(4)));
typedef unsigned short u16;
typedef unsigned int u32;

static __device__ __forceinline__ u16 f2bf(float f) {
  union { float f; unsigned u; } v; v.f = f;
  unsigned r = v.u + 0x7FFF + ((v.u >> 16) & 1);  // round-to-nearest-even
  return (u16)(r >> 16);
}
static __device__ __forceinline__ float bf2f(u16 h) {
  union { unsigned u; float f; } v; v.u = ((unsigned)h) << 16;
  return v.f;
}

// ---------- merged prep: binA | convertW | convertX | zero-row ----------
__global__ __launch_bounds__(1024) void prep_kernel(
    const int* __restrict__ src, const int* __restrict__ dst,
    const float* __restrict__ x, const float* __restrict__ W1,
    const float* __restrict__ W2, int* __restrict__ gcount,
    u32* __restrict__ bedge, u16* __restrict__ W1th, u16* __restrict__ W1tl,
    u16* __restrict__ W2th, u16* __restrict__ W2tl, u32* __restrict__ xb,
    u16* __restrict__ hb, int E, int nbk, int wtotal, int nPairs,
    int nA, int nB, int nC, int N) {
  __shared__ int cnt[128];
  __shared__ int base[128];
  int b = blockIdx.x, t = threadIdx.x;
  if (b < nA) {
    // binA: LDS-binned edge scatter into 512-node dst-buckets
    if (t < nbk) cnt[t] = 0;
    __syncthreads();
    int e = b * 1024 + t;
    int bk = 0, p = 0;
    u32 payload = 0;
    bool valid = e < E;
    if (valid) {
      int d = dst[e];
      bk = d >> 9;
      payload = ((u32)src[e] << 9) | (u32)(d & 511);
      p = atomicAdd(&cnt[bk], 1);      // LDS atomic
    }
    __syncthreads();
    if (t < nbk) base[t] = cnt[t] ? atomicAdd(&gcount[t], cnt[t]) : 0;
    __syncthreads();
    if (valid) {
      int pos = base[bk] + p;
      if (pos < BCAP) bedge[(size_t)bk * BCAP + pos] = payload;
    }
  } else if (b < nA + nB) {
    // convert weights: hi/lo split bf16 in MFMA-fragment-tiled order
    // ((kt*8+nt)*64+lane)*8+j  <-  W[k][n], k=kt*32+(lane>>4)*8+j, n=nt*16+(lane&15)
    int idx = (b - nA) * 1024 + t;
    if (idx < wtotal) {
      int l = idx >> 14;
      int r = idx & 16383;
      int j = r & 7;
      int lane = (r >> 3) & 63;
      int tt = r >> 9;
      int kt = tt >> 3, nt = tt & 7;
      int k = kt * 32 + (lane >> 4) * 8 + j;
      int n = nt * 16 + (lane & 15);
      size_t s = (size_t)l * D * D + (size_t)k * D + n;
      float w1 = W1[s], w2 = W2[s];
      u16 h1 = f2bf(w1), h2 = f2bf(w2);
      W1th[idx] = h1; W1tl[idx] = f2bf(w1 - bf2f(h1));
      W2th[idx] = h2; W2tl[idx] = f2bf(w2 - bf2f(h2));
    }
  } else if (b < nA + nB + nC) {
    // convert x -> bf16 packed pairs, 4 pairs/thread
    int i0 = (b - nA - nB) * 4096 + t * 4;
    if (i0 < nPairs) {
      float4 f0 = ((const float4*)x)[i0 >> 1];
      float4 f1 = ((const float4*)x)[(i0 >> 1) + 1];
      uint4 o;
      o.x = ((u32)f2bf(f0.y) << 16) | f2bf(f0.x);
      o.y = ((u32)f2bf(f0.w) << 16) | f2bf(f0.z);
      o.z = ((u32)f2bf(f1.y) << 16) | f2bf(f1.x);
      o.w = ((u32)f2bf(f1.w) << 16) | f2bf(f1.z);
      *(uint4*)(xb + i0) = o;
    }
  } else {
    // zero dummy row N of xb and hb
    if (t < 64) {
      ((u32*)xb)[(size_t)N * 64 + t] = 0;
      ((u32*)hb)[(size_t)N * 64 + t] = 0;
    }
  }
}

// ---------- binB: per-bucket slot assignment (LDS counters) + slot padding ----------
__global__ __launch_bounds__(1024) void binB_kernel(
    const int* __restrict__ gcount, const u32* __restrict__ bedge,
    int* __restrict__ deg, int* __restrict__ colidx, int N) {
  __shared__ int cnt2[512];
  int b = blockIdx.x;
  int t = threadIdx.x;
  if (t < 512) cnt2[t] = 0;
  __syncthreads();
  int count = min(gcount[b], BCAP);
  const u32* lst = bedge + (size_t)b * BCAP;
  for (int i = t; i < count; i += 1024) {
    u32 v = lst[i];
    int local = v & 511;
    int slot = atomicAdd(&cnt2[local], 1);   // LDS atomic
    if (slot < SLOTS)
      colidx[((size_t)(b << 9) + local) * CSTR + slot] = (int)(v >> 9);
  }
  __syncthreads();
  if (t < 512) {
    int node = (b << 9) + t;
    if (node < N) deg[node] = min(cnt2[t], SLOTS);
  }
  // pad slots [deg, CSTR) with dummy index N (zero row)
  for (int i = t; i < 512 * CSTR; i += 1024) {
    int local = i / CSTR;
    int slot = i - local * CSTR;
    int node = (b << 9) + local;
    if (node < N && slot >= min(cnt2[local], SLOTS))
      colidx[((size_t)(b << 9) + local) * CSTR + slot] = N;
  }
}

// ---------- aggregation: z = h + sum_{j->i} h[j]; 2 nodes/wave, uint2 gathers ----------
// lanes 0-31: node A, lanes 32-63: node B; each lane covers 4 cols (8B).
// Slot lists padded to CSTR with index N (zero row) -> branch-free 8-deep batches.
__global__ __launch_bounds__(256) void aggregate_kernel(
    const u16* __restrict__ hb, const int* __restrict__ deg,
    const int* __restrict__ colidx, u32* __restrict__ zb, int N) {
  int lane = threadIdx.x & 63;
  int sl = lane & 31;
  int node = blockIdx.x * 8 + (threadIdx.x >> 6) * 2 + (lane >> 5);
  bool live = node < N;
  int nodec = live ? node : N - 1;
  const uint2* hp = (const uint2*)hb;
  int e = live ? deg[node] : 0;
  int emax = max(e, __shfl_xor(e, 32, 64));
  uint2 s = hp[(size_t)(live ? node : N) * 32 + sl];
  float a0 = bf2f((u16)(s.x & 0xffff)), a1 = bf2f((u16)(s.x >> 16));
  float a2 = bf2f((u16)(s.y & 0xffff)), a3 = bf2f((u16)(s.y >> 16));
  const int* nbr = colidx + (size_t)nodec * CSTR;
  for (int k = 0; k < emax; k += 8) {
    int idx[8];
    uint2 v[8];
#pragma unroll
    for (int i = 0; i < 8; ++i) idx[i] = nbr[k + i];
#pragma unroll
    for (int i = 0; i < 8; ++i) v[i] = hp[(size_t)idx[i] * 32 + sl];
#pragma unroll
    for (int i = 0; i < 8; ++i) {
      a0 += bf2f((u16)(v[i].x & 0xffff));
      a1 += bf2f((u16)(v[i].x >> 16));
      a2 += bf2f((u16)(v[i].y & 0xffff));
      a3 += bf2f((u16)(v[i].y >> 16));
    }
  }
  if (live) {
    uint2 o;
    o.x = ((u32)f2bf(a1) << 16) | f2bf(a0);
    o.y = ((u32)f2bf(a3) << 16) | f2bf(a2);
    ((uint2*)zb)[(size_t)node * 32 + sl] = o;
  }
}

// ---------- GEMM: out = relu(A @ W + b), A bf16 [nrows][128] ----------
// W staged to LDS via REGULAR vector loads (L2-allocating) -- NOT global_load_lds:
// all blocks share the same 64KB W, so L2 hits matter more than the VGPR
// round-trip (DMA appeared to pull every block's copy across the L3 path).
// 256 rows/block x 512 thr, A-frags loaded before the barrier (r9-proven).
// Wave tiling: 2 m-tiles x 8 n-tiles, 2 MFMAs per product (a*wh + a*wl).
// LAST=0: write bf16. LAST=1: fused relu(.)·Wh dot -> atomic gsum[batch[row]].
template <int LAST>
__global__ __launch_bounds__(512) void gemm_kernel(
    const u16* __restrict__ A, const u16* __restrict__ Wth, const u16* __restrict__ Wtl,
    const float* __restrict__ bias, u16* __restrict__ outp,
    const float* __restrict__ Wh, const int* __restrict__ batch, float* __restrict__ gsum,
    int nrows) {
  __shared__ __attribute__((aligned(16))) u16 ldsWh[16384];
  __shared__ __attribute__((aligned(16))) u16 ldsWl[16384];
  int tid = threadIdx.x;
  {
    const uint4* gh = (const uint4*)Wth;
    const uint4* gl = (const uint4*)Wtl;
    uint4* lh = (uint4*)ldsWh;
    uint4* ll = (uint4*)ldsWl;
    uint4 th[4], tl[4];
#pragma unroll
    for (int i = 0; i < 4; ++i) { th[i] = gh[tid + i * 512]; tl[i] = gl[tid + i * 512]; }
#pragma unroll
    for (int i = 0; i < 4; ++i) { lh[tid + i * 512] = th[i]; ll[tid + i * 512] = tl[i]; }
  }
  int wave = tid >> 6, lane = tid & 63;
  int quad = lane >> 4, l16 = lane & 15;
  int rowbase = blockIdx.x * 256 + wave * 32;
  int mc0 = min(rowbase + l16, nrows - 1);
  int mc1 = min(rowbase + 16 + l16, nrows - 1);

  // preload all A-fragments; latency hides behind the staging drain at the barrier
  short8 a0[4], a1[4];
#pragma unroll
  for (int kt = 0; kt < 4; ++kt) {
    a0[kt] = *(const short8*)(A + (size_t)mc0 * D + kt * 32 + quad * 8);
    a1[kt] = *(const short8*)(A + (size_t)mc1 * D + kt * 32 + quad * 8);
  }

  __syncthreads();

  f32x4 acc[2][8];
  f32x4 zero = {0.f, 0.f, 0.f, 0.f};
#pragma unroll
  for (int mt = 0; mt < 2; ++mt)
#pragma unroll
    for (int nt = 0; nt < 8; ++nt) acc[mt][nt] = zero;

#pragma unroll
  for (int kt = 0; kt < 4; ++kt) {
#pragma unroll
    for (int nt = 0; nt < 8; ++nt) {
      int fo = ((kt * 8 + nt) * 64 + lane) * 8;
      short8 bh = *(const short8*)(ldsWh + fo);
      short8 bl = *(const short8*)(ldsWl + fo);
      acc[0][nt] = __builtin_amdgcn_mfma_f32_16x16x32_bf16(a0[kt], bh, acc[0][nt], 0, 0, 0);
      acc[0][nt] = __builtin_amdgcn_mfma_f32_16x16x32_bf16(a0[kt], bl, acc[0][nt], 0, 0, 0);
      acc[1][nt] = __builtin_amdgcn_mfma_f32_16x16x32_bf16(a1[kt], bh, acc[1][nt], 0, 0, 0);
      acc[1][nt] = __builtin_amdgcn_mfma_f32_16x16x32_bf16(a1[kt], bl, acc[1][nt], 0, 0, 0);
    }
  }

  if (LAST) {
    float dotr[2][4] = {{0.f, 0.f, 0.f, 0.f}, {0.f, 0.f, 0.f, 0.f}};
#pragma unroll
    for (int nt = 0; nt < 8; ++nt) {
      int col = nt * 16 + l16;
      float bv = bias[col];
      float wv = Wh[col];
#pragma unroll
      for (int mt = 0; mt < 2; ++mt)
#pragma unroll
        for (int r = 0; r < 4; ++r)
          dotr[mt][r] += fmaxf(acc[mt][nt][r] + bv, 0.f) * wv;
    }
#pragma unroll
    for (int m = 1; m < 16; m <<= 1) {
#pragma unroll
      for (int mt = 0; mt < 2; ++mt)
#pragma unroll
        for (int r = 0; r < 4; ++r) dotr[mt][r] += __shfl_xor(dotr[mt][r], m, 64);
    }
    if (l16 == 0) {
#pragma unroll
      for (int mt = 0; mt < 2; ++mt)
#pragma unroll
        for (int r = 0; r < 4; ++r) {
          int row = rowbase + mt * 16 + quad * 4 + r;
          if (row < nrows) atomicAdd(&gsum[batch[row]], dotr[mt][r]);
        }
    }
  } else {
#pragma unroll
    for (int nt = 0; nt < 8; ++nt) {
      int col = nt * 16 + l16;
      float bv = bias[col];
#pragma unroll
      for (int mt = 0; mt < 2; ++mt)
#pragma unroll
        for (int r = 0; r < 4; ++r) {
          int row = rowbase + mt * 16 + quad * 4 + r;
          if (row < nrows)
            outp[(size_t)row * D + col] = f2bf(fmaxf(acc[mt][nt][r] + bv, 0.f));
        }
    }
  }
}

// ---------- finalize: per-graph mean via binary search on sorted batch ----------
__global__ void pool_final_kernel(const float* __restrict__ gsum, const int* __restrict__ batch,
                                  const float* __restrict__ bh, float* __restrict__ out,
                                  int G, int N) {
  int g = blockIdx.x * 256 + threadIdx.x;
  if (g >= G) return;
  int lo = 0, hi = N;
  while (lo < hi) { int mid = (lo + hi) >> 1; if (batch[mid] < g) lo = mid + 1; else hi = mid; }
  int lo2 = lo, hi2 = N;
  while (lo2 < hi2) { int mid = (lo2 + hi2) >> 1; if (batch[mid] < g + 1) lo2 = mid + 1; else hi2 = mid; }
  int c = lo2 - lo;
  out[g] = gsum[g] / fmaxf((float)c, 1.f) + bh[0];
}

extern "C" void kernel_launch(void* const* d_in, const int* in_sizes, int n_in,
                              void* d_out, int out_size, void* d_ws, size_t ws_size,
                              hipStream_t stream) {
  const float* x   = (const float*)d_in[0];
  const int* eidx  = (const int*)d_in[1];
  const int* batch = (const int*)d_in[2];
  const float* W1s = (const float*)d_in[3];
  const float* b1s = (const float*)d_in[4];
  const float* W2s = (const float*)d_in[5];
  const float* b2s = (const float*)d_in[6];
  const float* Wh  = (const float*)d_in[7];
  const float* bh  = (const float*)d_in[8];
  float* out = (float*)d_out;

  int N = in_sizes[0] / D;
  int E = in_sizes[1] / 2;
  int G = out_size;
  int L = in_sizes[3] / (D * D);
  int nbk = (N + 511) >> 9;           // 512-node dst-buckets (<=128)
  int wtotal = L * D * D;
  int nPairs = N * D / 2;

  const int* src = eidx;
  const int* dst = eidx + E;

  char* p = (char*)d_ws;
  auto alloc = [&](size_t b) { char* r = p; p += (b + 255) & ~(size_t)255; return r; };
  u16*   hb     = (u16*)  alloc((size_t)(N + 1) * D * 2);   // +1 zero row
  u16*   xb     = (u16*)  alloc((size_t)(N + 1) * D * 2);   // +1 zero row
  u16*   zb     = (u16*)  alloc((size_t)N * D * 2);
  u16*   yb     = (u16*)  alloc((size_t)N * D * 2);
  size_t zbytes = (size_t)G * 4 + 512;                       // gsum + gcount
  char*  zblk   =         alloc(zbytes);
  float* gsum   = (float*)zblk;
  int*   gcount = (int*)(zblk + (size_t)G * 4);
  int*   deg    = (int*)  alloc((size_t)N * 4);
  int*   colidx = (int*)  alloc((size_t)N * CSTR * 4);
  u32*   bedge  = (u32*)  alloc((size_t)128 * BCAP * 4);
  u16*   W1th   = (u16*)  alloc((size_t)L * D * D * 2);
  u16*   W1tl   = (u16*)  alloc((size_t)L * D * D * 2);
  u16*   W2th   = (u16*)  alloc((size_t)L * D * D * 2);
  u16*   W2tl   = (u16*)  alloc((size_t)L * D * D * 2);

  hipMemsetAsync(zblk, 0, zbytes, stream);

  int nA = (E + 1023) / 1024;
  int nB = (wtotal + 1023) / 1024;
  int nC = (nPairs / 4 + 1023) / 1024;
  prep_kernel<<<nA + nB + nC + 1, 1024, 0, stream>>>(
      src, dst, x, W1s, W2s, gcount, bedge, W1th, W1tl, W2th, W2tl,
      (u32*)xb, hb, E, nbk, wtotal, nPairs, nA, nB, nC, N);
  binB_kernel<<<nbk, 1024, 0, stream>>>(gcount, bedge, deg, colidx, N);

  int gemm_blocks = (N + 255) / 256;
  for (int l = 0; l < L; ++l) {
    const u16* hin = (l == 0) ? xb : hb;
    aggregate_kernel<<<(N + 7) / 8, 256, 0, stream>>>(hin, deg, colidx, (u32*)zb, N);
    size_t wo = (size_t)l * D * D;
    gemm_kernel<0><<<gemm_blocks, 512, 0, stream>>>(
        zb, W1th + wo, W1tl + wo, b1s + (size_t)l * D, yb,
        nullptr, nullptr, nullptr, N);
    if (l < L - 1) {
      gemm_kernel<0><<<gemm_blocks, 512, 0, stream>>>(
          yb, W2th + wo, W2tl + wo, b2s + (size_t)l * D, hb,
          nullptr, nullptr, nullptr, N);
    } else {
      gemm_kernel<1><<<gemm_blocks, 512, 0, stream>>>(
          yb, W2th + wo, W2tl + wo, b2s + (size_t)l * D, nullptr,
          Wh, batch, gsum, N);
    }
  }
  pool_final_kernel<<<(G + 255) / 256, 256, 0, stream>>>(gsum, batch, bh, out, G, N);
}